// Round 1
// baseline (526.622 us; speedup 1.0000x reference)
//
#include <hip/hip_runtime.h>
#include <math.h>

#define B_ 4
#define N_ 16384
#define M_ 1024
#define C_ 64

// output layout (floats): new_xyz [B*M*3] | feats [B*256*M] | inds [B*M]
#define OUT_XYZ_ELEMS (B_ * M_ * 3)
#define OUT_FEAT_ELEMS (B_ * 256 * M_)

// ------------------------------------------------------------------
// gather centers + write inds (as float) to d_out
__global__ void k_gather(const float* __restrict__ xyz, const int* __restrict__ inds,
                         float* __restrict__ out) {
    int t = blockIdx.x * blockDim.x + threadIdx.x;
    if (t >= B_ * M_) return;
    int n = inds[t];
    int b = t / M_;
    const float* p = xyz + ((size_t)b * N_ + n) * 3;
    out[t * 3 + 0] = p[0];
    out[t * 3 + 1] = p[1];
    out[t * 3 + 2] = p[2];
    out[OUT_XYZ_ELEMS + OUT_FEAT_ELEMS + t] = (float)n;
}

// ------------------------------------------------------------------
// ball query: one wave (64 lanes) per query point.
// semantics: first NS indices (ascending) with d2 < r2; pad with first found.
__global__ void k_ball(const float* __restrict__ xyz, const int* __restrict__ inds,
                       int* __restrict__ idxbuf, float r2, int NS) {
    int lane = threadIdx.x & 63;
    int t = blockIdx.x * (blockDim.x >> 6) + (threadIdx.x >> 6);
    if (t >= B_ * M_) return;
    int b = t / M_;
    int n0 = inds[t];
    const float* bp = xyz + (size_t)b * N_ * 3;
    float qx = bp[n0 * 3 + 0], qy = bp[n0 * 3 + 1], qz = bp[n0 * 3 + 2];
    int cnt = 0;
    int first = n0;
    for (int base = 0; base < N_ && cnt < NS; base += 64) {
        int n = base + lane;
        float dx = __fsub_rn(qx, bp[n * 3 + 0]);
        float dy = __fsub_rn(qy, bp[n * 3 + 1]);
        float dz = __fsub_rn(qz, bp[n * 3 + 2]);
        float d2 = __fadd_rn(__fadd_rn(__fmul_rn(dx, dx), __fmul_rn(dy, dy)), __fmul_rn(dz, dz));
        unsigned long long mask = __ballot(d2 < r2);
        while (mask && cnt < NS) {
            int bit = (int)__builtin_ctzll(mask);
            int nn = base + bit;
            if (cnt == 0) first = nn;
            if (lane == 0) idxbuf[t * NS + cnt] = nn;
            cnt++;
            mask &= mask - 1;
        }
    }
    for (int k2 = cnt + lane; k2 < NS; k2 += 64) idxbuf[t * NS + k2] = first;
}

// ------------------------------------------------------------------
// build grouped input X[c][j], c in [0,67), j = (b*M+m)*NS + s
__global__ void k_group(const float* __restrict__ xyz, const float* __restrict__ feats,
                        const float* __restrict__ newxyz, const int* __restrict__ idxbuf,
                        float* __restrict__ X, int NS, int Nj) {
    int j = blockIdx.x * blockDim.x + threadIdx.x;
    if (j >= Nj) return;
    int bm = j / NS;
    int b = bm / M_;
    int nidx = idxbuf[j];
    const float* p = xyz + ((size_t)b * N_ + nidx) * 3;
    X[(size_t)0 * Nj + j] = p[0] - newxyz[bm * 3 + 0];
    X[(size_t)1 * Nj + j] = p[1] - newxyz[bm * 3 + 1];
    X[(size_t)2 * Nj + j] = p[2] - newxyz[bm * 3 + 2];
    const float* f = feats + (size_t)b * C_ * N_ + nidx;
    #pragma unroll 8
    for (int c = 0; c < C_; ++c)
        X[(size_t)(3 + c) * Nj + j] = f[(size_t)c * N_];
}

// ------------------------------------------------------------------
// GEMM: Y[o][j] = sum_c W[o][c] * X[c][j].  cout = KO*16. 256 threads.
// block tile: cout x 128 j.  W fully in LDS (transposed), X staged 8x128.
template <int KO>
__global__ __launch_bounds__(256) void k_gemm(const float* __restrict__ W,
                                              const float* __restrict__ X,
                                              float* __restrict__ Y, int cin, int Nj) {
    const int cout = KO * 16;
    __shared__ float Wl[96 * 128];   // [c][o]
    __shared__ float Xl[8][128];

    // stage W transposed
    for (int e = threadIdx.x; e < cin * cout; e += 256) {
        int o = e / cin;
        int c = e - o * cin;
        Wl[c * cout + o] = W[e];
    }

    int tx = threadIdx.x & 15;
    int ty = threadIdx.x >> 4;
    int j0 = blockIdx.x * 128;

    float acc[KO][8];
    #pragma unroll
    for (int k = 0; k < KO; ++k)
        #pragma unroll
        for (int q = 0; q < 8; ++q) acc[k][q] = 0.f;

    int stage_r = threadIdx.x >> 5;           // 0..7
    int stage_c4 = (threadIdx.x & 31) * 4;    // 0..124

    int cfull = cin & ~7;
    for (int c0 = 0; c0 < cfull; c0 += 8) {
        __syncthreads();
        *(float4*)&Xl[stage_r][stage_c4] =
            *(const float4*)&X[(size_t)(c0 + stage_r) * Nj + j0 + stage_c4];
        __syncthreads();
        #pragma unroll
        for (int cc = 0; cc < 8; ++cc) {
            float4 xa = *(const float4*)&Xl[cc][tx * 4];
            float4 xb = *(const float4*)&Xl[cc][tx * 4 + 64];
            #pragma unroll
            for (int k = 0; k < KO; ++k) {
                float w = Wl[(c0 + cc) * cout + ty + 16 * k];
                acc[k][0] += w * xa.x; acc[k][1] += w * xa.y;
                acc[k][2] += w * xa.z; acc[k][3] += w * xa.w;
                acc[k][4] += w * xb.x; acc[k][5] += w * xb.y;
                acc[k][6] += w * xb.z; acc[k][7] += w * xb.w;
            }
        }
    }
    int crem = cin - cfull;
    if (crem) {
        __syncthreads();
        if (stage_r < crem)
            *(float4*)&Xl[stage_r][stage_c4] =
                *(const float4*)&X[(size_t)(cfull + stage_r) * Nj + j0 + stage_c4];
        __syncthreads();
        for (int cc = 0; cc < crem; ++cc) {
            float4 xa = *(const float4*)&Xl[cc][tx * 4];
            float4 xb = *(const float4*)&Xl[cc][tx * 4 + 64];
            #pragma unroll
            for (int k = 0; k < KO; ++k) {
                float w = Wl[(cfull + cc) * cout + ty + 16 * k];
                acc[k][0] += w * xa.x; acc[k][1] += w * xa.y;
                acc[k][2] += w * xa.z; acc[k][3] += w * xa.w;
                acc[k][4] += w * xb.x; acc[k][5] += w * xb.y;
                acc[k][6] += w * xb.z; acc[k][7] += w * xb.w;
            }
        }
    }

    #pragma unroll
    for (int k = 0; k < KO; ++k) {
        int o = ty + 16 * k;
        float4 v0 = make_float4(acc[k][0], acc[k][1], acc[k][2], acc[k][3]);
        float4 v1 = make_float4(acc[k][4], acc[k][5], acc[k][6], acc[k][7]);
        *(float4*)&Y[(size_t)o * Nj + j0 + tx * 4] = v0;
        *(float4*)&Y[(size_t)o * Nj + j0 + 64 + tx * 4] = v1;
    }
}

// ------------------------------------------------------------------
// per-channel batch stats -> scale/shift.  one block per channel.
__global__ __launch_bounds__(256) void k_stats(const float* __restrict__ Y,
                                               const float* __restrict__ gam,
                                               const float* __restrict__ bet,
                                               float* __restrict__ ss, int Nj) {
    int o = blockIdx.x;
    const float* row = Y + (size_t)o * Nj;
    float s = 0.f, s2 = 0.f;
    for (int i = threadIdx.x * 4; i < Nj; i += 256 * 4) {
        float4 v = *(const float4*)&row[i];
        s += v.x + v.y + v.z + v.w;
        s2 += v.x * v.x + v.y * v.y + v.z * v.z + v.w * v.w;
    }
    #pragma unroll
    for (int off = 1; off < 64; off <<= 1) {
        s += __shfl_xor(s, off, 64);
        s2 += __shfl_xor(s2, off, 64);
    }
    __shared__ float ls[4], ls2[4];
    int wid = threadIdx.x >> 6;
    if ((threadIdx.x & 63) == 0) { ls[wid] = s; ls2[wid] = s2; }
    __syncthreads();
    if (threadIdx.x == 0) {
        float S = ls[0] + ls[1] + ls[2] + ls[3];
        float S2 = ls2[0] + ls2[1] + ls2[2] + ls2[3];
        float inv = 1.0f / (float)Nj;
        float mean = S * inv;
        float var = S2 * inv - mean * mean;
        float scale = gam[o] / sqrtf(var + 1e-5f);
        float shift = bet[o] - mean * scale;
        ss[o * 2 + 0] = scale;
        ss[o * 2 + 1] = shift;
    }
}

// ------------------------------------------------------------------
// in-place normalize + ReLU
__global__ void k_norm(float* __restrict__ Y, const float* __restrict__ ss, int Nj) {
    size_t e = ((size_t)blockIdx.x * blockDim.x + threadIdx.x) * 4;
    int o = (int)(e / (size_t)Nj);
    float sc = ss[o * 2 + 0], sh = ss[o * 2 + 1];
    float4 v = *(float4*)&Y[e];
    v.x = fmaxf(v.x * sc + sh, 0.f);
    v.y = fmaxf(v.y * sc + sh, 0.f);
    v.z = fmaxf(v.z * sc + sh, 0.f);
    v.w = fmaxf(v.w * sc + sh, 0.f);
    *(float4*)&Y[e] = v;
}

// ------------------------------------------------------------------
// fused BN + ReLU + maxpool over samples for the last layer (cout=128)
__global__ void k_maxpool(const float* __restrict__ Y, const float* __restrict__ ss,
                          float* __restrict__ out, int NS, int Nj, int o_off) {
    int t = blockIdx.x * blockDim.x + threadIdx.x;  // ((b*128+o)*M + m)
    if (t >= B_ * 128 * M_) return;
    int m = t & (M_ - 1);
    int bo = t >> 10;
    int o = bo & 127;
    int b = bo >> 7;
    float sc = ss[o * 2 + 0], sh = ss[o * 2 + 1];
    const float* p = Y + (size_t)o * Nj + (size_t)(b * M_ + m) * NS;
    float mx = -INFINITY;
    for (int s4 = 0; s4 < NS; s4 += 4) {
        float4 v = *(const float4*)&p[s4];
        mx = fmaxf(mx, v.x * sc + sh);
        mx = fmaxf(mx, v.y * sc + sh);
        mx = fmaxf(mx, v.z * sc + sh);
        mx = fmaxf(mx, v.w * sc + sh);
    }
    out[OUT_XYZ_ELEMS + ((size_t)(b * 256 + o_off + o)) * M_ + m] = fmaxf(mx, 0.f);
}

// ------------------------------------------------------------------
extern "C" void kernel_launch(void* const* d_in, const int* in_sizes, int n_in,
                              void* d_out, int out_size, void* d_ws, size_t ws_size,
                              hipStream_t stream) {
    const float* xyz = (const float*)d_in[0];
    const float* feats = (const float*)d_in[1];
    const int* inds = (const int*)d_in[2];
    const float* w[2][3];
    const float* gg[2][3];
    const float* bb[2][3];
    int k = 3;
    for (int i = 0; i < 2; ++i)
        for (int l = 0; l < 3; ++l) {
            w[i][l] = (const float*)d_in[k++];
            gg[i][l] = (const float*)d_in[k++];
            bb[i][l] = (const float*)d_in[k++];
        }
    float* out = (float*)d_out;

    const size_t NJ1 = (size_t)B_ * M_ * 32;        // 131072
    float* bufA = (float*)d_ws;                     // 96 rows  x 131072
    float* bufB = bufA + 96 * NJ1;                  // 128 rows x 131072
    int* idxbuf = (int*)(bufB + 128 * NJ1);         // B*M*32 ints
    float* ss = (float*)(idxbuf + B_ * M_ * 32);    // 128*2 floats

    k_gather<<<16, 256, 0, stream>>>(xyz, inds, out);

    // ---------- scale 0: r=0.4, ns=16, layers 67->64->64->128 ----------
    {
        const int NS = 16;
        const int Nj = B_ * M_ * NS;  // 65536
        k_ball<<<1024, 256, 0, stream>>>(xyz, inds, idxbuf, (float)(0.4 * 0.4), NS);
        k_group<<<Nj / 256, 256, 0, stream>>>(xyz, feats, out, idxbuf, bufA, NS, Nj);
        k_gemm<4><<<Nj / 128, 256, 0, stream>>>(w[0][0], bufA, bufB, 67, Nj);
        k_stats<<<64, 256, 0, stream>>>(bufB, gg[0][0], bb[0][0], ss, Nj);
        k_norm<<<(64 * Nj / 4) / 256, 256, 0, stream>>>(bufB, ss, Nj);
        k_gemm<4><<<Nj / 128, 256, 0, stream>>>(w[0][1], bufB, bufA, 64, Nj);
        k_stats<<<64, 256, 0, stream>>>(bufA, gg[0][1], bb[0][1], ss, Nj);
        k_norm<<<(64 * Nj / 4) / 256, 256, 0, stream>>>(bufA, ss, Nj);
        k_gemm<8><<<Nj / 128, 256, 0, stream>>>(w[0][2], bufA, bufB, 64, Nj);
        k_stats<<<128, 256, 0, stream>>>(bufB, gg[0][2], bb[0][2], ss, Nj);
        k_maxpool<<<(B_ * 128 * M_) / 256, 256, 0, stream>>>(bufB, ss, out, NS, Nj, 0);
    }

    // ---------- scale 1: r=0.8, ns=32, layers 67->64->96->128 ----------
    {
        const int NS = 32;
        const int Nj = B_ * M_ * NS;  // 131072
        k_ball<<<1024, 256, 0, stream>>>(xyz, inds, idxbuf, (float)(0.8 * 0.8), NS);
        k_group<<<Nj / 256, 256, 0, stream>>>(xyz, feats, out, idxbuf, bufA, NS, Nj);
        k_gemm<4><<<Nj / 128, 256, 0, stream>>>(w[1][0], bufA, bufB, 67, Nj);
        k_stats<<<64, 256, 0, stream>>>(bufB, gg[1][0], bb[1][0], ss, Nj);
        k_norm<<<(64 * Nj / 4) / 256, 256, 0, stream>>>(bufB, ss, Nj);
        k_gemm<6><<<Nj / 128, 256, 0, stream>>>(w[1][1], bufB, bufA, 64, Nj);
        k_stats<<<96, 256, 0, stream>>>(bufA, gg[1][1], bb[1][1], ss, Nj);
        k_norm<<<(96 * Nj / 4) / 256, 256, 0, stream>>>(bufA, ss, Nj);
        k_gemm<8><<<Nj / 128, 256, 0, stream>>>(w[1][2], bufA, bufB, 96, Nj);
        k_stats<<<128, 256, 0, stream>>>(bufB, gg[1][2], bb[1][2], ss, Nj);
        k_maxpool<<<(B_ * 128 * M_) / 256, 256, 0, stream>>>(bufB, ss, out, NS, Nj, 128);
    }
}

// Round 2
// 253.972 us; speedup vs baseline: 2.0735x; 2.0735x over previous
//
#include <hip/hip_runtime.h>
#include <math.h>

#define B_ 4
#define N_ 16384
#define M_ 1024
#define C_ 64

// output layout (floats): new_xyz [B*M*3] | feats [B*256*M] | inds [B*M]
#define OUT_XYZ_ELEMS (B_ * M_ * 3)
#define OUT_FEAT_ELEMS (B_ * 256 * M_)
#define GXMAX 1024

// ------------------------------------------------------------------
// gather centers + write inds (as float) to d_out
__global__ void k_gather(const float* __restrict__ xyz, const int* __restrict__ inds,
                         float* __restrict__ out) {
    int t = blockIdx.x * blockDim.x + threadIdx.x;
    if (t >= B_ * M_) return;
    int n = inds[t];
    int b = t / M_;
    const float* p = xyz + ((size_t)b * N_ + n) * 3;
    out[t * 3 + 0] = p[0];
    out[t * 3 + 1] = p[1];
    out[t * 3 + 2] = p[2];
    out[OUT_XYZ_ELEMS + OUT_FEAT_ELEMS + t] = (float)n;
}

// ------------------------------------------------------------------
// ball query: one wave (64 lanes) per query point.
__global__ void k_ball(const float* __restrict__ xyz, const int* __restrict__ inds,
                       int* __restrict__ idxbuf, float r2, int NS) {
    int lane = threadIdx.x & 63;
    int t = blockIdx.x * (blockDim.x >> 6) + (threadIdx.x >> 6);
    if (t >= B_ * M_) return;
    int b = t / M_;
    int n0 = inds[t];
    const float* bp = xyz + (size_t)b * N_ * 3;
    float qx = bp[n0 * 3 + 0], qy = bp[n0 * 3 + 1], qz = bp[n0 * 3 + 2];
    int cnt = 0;
    int first = n0;
    for (int base = 0; base < N_ && cnt < NS; base += 64) {
        int n = base + lane;
        float dx = __fsub_rn(qx, bp[n * 3 + 0]);
        float dy = __fsub_rn(qy, bp[n * 3 + 1]);
        float dz = __fsub_rn(qz, bp[n * 3 + 2]);
        float d2 = __fadd_rn(__fadd_rn(__fmul_rn(dx, dx), __fmul_rn(dy, dy)), __fmul_rn(dz, dz));
        unsigned long long mask = __ballot(d2 < r2);
        while (mask && cnt < NS) {
            int bit = (int)__builtin_ctzll(mask);
            int nn = base + bit;
            if (cnt == 0) first = nn;
            if (lane == 0) idxbuf[t * NS + cnt] = nn;
            cnt++;
            mask &= mask - 1;
        }
    }
    for (int k2 = cnt + lane; k2 < NS; k2 += 64) idxbuf[t * NS + k2] = first;
}

// ------------------------------------------------------------------
// build grouped input X[c][j], c in [0,67), j = (b*M+m)*NS + s
__global__ void k_group(const float* __restrict__ xyz, const float* __restrict__ feats,
                        const float* __restrict__ newxyz, const int* __restrict__ idxbuf,
                        float* __restrict__ X, int NS, int Nj) {
    int j = blockIdx.x * blockDim.x + threadIdx.x;
    if (j >= Nj) return;
    int bm = j / NS;
    int b = bm / M_;
    int nidx = idxbuf[j];
    const float* p = xyz + ((size_t)b * N_ + nidx) * 3;
    X[(size_t)0 * Nj + j] = p[0] - newxyz[bm * 3 + 0];
    X[(size_t)1 * Nj + j] = p[1] - newxyz[bm * 3 + 1];
    X[(size_t)2 * Nj + j] = p[2] - newxyz[bm * 3 + 2];
    const float* f = feats + (size_t)b * C_ * N_ + nidx;
    #pragma unroll 8
    for (int c = 0; c < C_; ++c)
        X[(size_t)(3 + c) * Nj + j] = f[(size_t)c * N_];
}

// ------------------------------------------------------------------
// GEMM: Y[o][j] = sum_c W[o][c] * x[c][j], with optional BN+ReLU applied to
// X while staging (x = relu(sc*X+sh)).  Block tile: COB=KO*16 channels x 128 j.
// Epilogue: per-channel block partial sums (for BN stats of THIS layer) and
// either full Y write or fused max-pool over NSPOOL samples (valid since
// gamma=1 => scale>0 => max commutes with affine+relu).
template <int KO, bool BN, int NSPOOL>
__global__ __launch_bounds__(256) void k_gemm(const float* __restrict__ W,
                                              const float* __restrict__ X,
                                              const float* __restrict__ ssin,
                                              float* __restrict__ Y,
                                              float* __restrict__ pS,
                                              float* __restrict__ pS2,
                                              int cin, int Nj) {
    const int COB = KO * 16;
    __shared__ float Wl[6144];      // [c][(o%16)*KO + o/16], cin*COB <= 6144
    __shared__ float Xl[8][128];

    const int oy = blockIdx.y;
    const float* Wp = W + (size_t)oy * COB * cin;

    // stage W: consecutive threads take consecutive o -> conflict-free LDS writes
    for (int e = threadIdx.x; e < cin * COB; e += 256) {
        int o = e % COB;
        int c = e / COB;
        Wl[c * COB + (o & 15) * KO + (o >> 4)] = Wp[o * cin + c];
    }

    const int tx = threadIdx.x & 15;
    const int ty = threadIdx.x >> 4;
    const int j0 = blockIdx.x * 128;

    float acc[KO][8];
    #pragma unroll
    for (int k = 0; k < KO; ++k)
        #pragma unroll
        for (int q = 0; q < 8; ++q) acc[k][q] = 0.f;

    const int stage_r = threadIdx.x >> 5;         // 0..7
    const int stage_c4 = (threadIdx.x & 31) * 4;  // 0..124

    const int cfull = cin & ~7;
    for (int c0 = 0; c0 <= cfull; c0 += 8) {
        const int crem = (c0 < cfull) ? 8 : (cin - cfull);
        if (crem == 0) break;
        __syncthreads();
        if (stage_r < crem) {
            int c = c0 + stage_r;
            float4 v = *(const float4*)&X[(size_t)c * Nj + j0 + stage_c4];
            if (BN) {
                float sc = ssin[c * 2 + 0], sh = ssin[c * 2 + 1];
                v.x = fmaxf(fmaf(v.x, sc, sh), 0.f);
                v.y = fmaxf(fmaf(v.y, sc, sh), 0.f);
                v.z = fmaxf(fmaf(v.z, sc, sh), 0.f);
                v.w = fmaxf(fmaf(v.w, sc, sh), 0.f);
            }
            *(float4*)&Xl[stage_r][stage_c4] = v;
        }
        __syncthreads();
        for (int cc = 0; cc < crem; ++cc) {
            float4 xa = *(const float4*)&Xl[cc][tx * 4];
            float4 xb = *(const float4*)&Xl[cc][tx * 4 + 64];
            #pragma unroll
            for (int k = 0; k < KO; ++k) {
                float w = Wl[(c0 + cc) * COB + ty * KO + k];
                acc[k][0] += w * xa.x; acc[k][1] += w * xa.y;
                acc[k][2] += w * xa.z; acc[k][3] += w * xa.w;
                acc[k][4] += w * xb.x; acc[k][5] += w * xb.y;
                acc[k][6] += w * xb.z; acc[k][7] += w * xb.w;
            }
        }
    }

    const int gx = gridDim.x;
    #pragma unroll
    for (int k = 0; k < KO; ++k) {
        int o = oy * COB + ty + 16 * k;
        // per-channel partial stats over this block's 128 columns
        float s = 0.f, s2 = 0.f;
        #pragma unroll
        for (int q = 0; q < 8; ++q) { s += acc[k][q]; s2 += acc[k][q] * acc[k][q]; }
        #pragma unroll
        for (int off = 1; off < 16; off <<= 1) {
            s += __shfl_xor(s, off);
            s2 += __shfl_xor(s2, off);
        }
        if (tx == 0) {
            pS[(size_t)o * GXMAX + blockIdx.x] = s;
            pS2[(size_t)o * GXMAX + blockIdx.x] = s2;
        }
        if (NSPOOL == 0) {
            *(float4*)&Y[(size_t)o * Nj + j0 + tx * 4] =
                make_float4(acc[k][0], acc[k][1], acc[k][2], acc[k][3]);
            *(float4*)&Y[(size_t)o * Nj + j0 + 64 + tx * 4] =
                make_float4(acc[k][4], acc[k][5], acc[k][6], acc[k][7]);
        } else {
            const int L = NSPOOL / 4;           // lanes per (b,m) group
            float mA = fmaxf(fmaxf(acc[k][0], acc[k][1]), fmaxf(acc[k][2], acc[k][3]));
            float mB = fmaxf(fmaxf(acc[k][4], acc[k][5]), fmaxf(acc[k][6], acc[k][7]));
            #pragma unroll
            for (int off = 1; off < L; off <<= 1) {
                mA = fmaxf(mA, __shfl_xor(mA, off));
                mB = fmaxf(mB, __shfl_xor(mB, off));
            }
            if ((tx & (L - 1)) == 0) {
                int bm0 = j0 / NSPOOL;
                int g = tx / L;
                Y[(size_t)o * (B_ * M_) + bm0 + g] = mA;                  // Ymax
                Y[(size_t)o * (B_ * M_) + bm0 + g + 64 / NSPOOL] = mB;
            }
        }
    }
}

// ------------------------------------------------------------------
// reduce per-block partials -> scale/shift for channel blockIdx.x
__global__ __launch_bounds__(256) void k_fin(const float* __restrict__ pS,
                                             const float* __restrict__ pS2,
                                             const float* __restrict__ gam,
                                             const float* __restrict__ bet,
                                             float* __restrict__ ss, int gx, float invN) {
    int o = blockIdx.x;
    float s = 0.f, s2 = 0.f;
    for (int i = threadIdx.x; i < gx; i += 256) {
        s += pS[(size_t)o * GXMAX + i];
        s2 += pS2[(size_t)o * GXMAX + i];
    }
    #pragma unroll
    for (int off = 1; off < 64; off <<= 1) {
        s += __shfl_xor(s, off, 64);
        s2 += __shfl_xor(s2, off, 64);
    }
    __shared__ float ls[4], ls2[4];
    int wid = threadIdx.x >> 6;
    if ((threadIdx.x & 63) == 0) { ls[wid] = s; ls2[wid] = s2; }
    __syncthreads();
    if (threadIdx.x == 0) {
        float S = ls[0] + ls[1] + ls[2] + ls[3];
        float S2 = ls2[0] + ls2[1] + ls2[2] + ls2[3];
        float mean = S * invN;
        float var = S2 * invN - mean * mean;
        float scale = gam[o] / sqrtf(var + 1e-5f);
        float shift = bet[o] - mean * scale;
        ss[o * 2 + 0] = scale;
        ss[o * 2 + 1] = shift;
    }
}

// ------------------------------------------------------------------
// apply BN+ReLU to pooled raw maxima and write final features
__global__ void k_poolfin(const float* __restrict__ Ymax, const float* __restrict__ ss,
                          float* __restrict__ out, int o_off) {
    int t = blockIdx.x * blockDim.x + threadIdx.x;
    if (t >= B_ * 128 * M_) return;
    int m = t & (M_ - 1);
    int o = (t >> 10) & 127;
    int b = t >> 17;
    float sc = ss[o * 2 + 0], sh = ss[o * 2 + 1];
    float v = Ymax[(size_t)o * (B_ * M_) + b * M_ + m];
    out[OUT_XYZ_ELEMS + ((size_t)(b * 256 + o_off + o)) * M_ + m] = fmaxf(fmaf(v, sc, sh), 0.f);
}

// ------------------------------------------------------------------
extern "C" void kernel_launch(void* const* d_in, const int* in_sizes, int n_in,
                              void* d_out, int out_size, void* d_ws, size_t ws_size,
                              hipStream_t stream) {
    const float* xyz = (const float*)d_in[0];
    const float* feats = (const float*)d_in[1];
    const int* inds = (const int*)d_in[2];
    const float* w[2][3];
    const float* gg[2][3];
    const float* bb[2][3];
    int k = 3;
    for (int i = 0; i < 2; ++i)
        for (int l = 0; l < 3; ++l) {
            w[i][l] = (const float*)d_in[k++];
            gg[i][l] = (const float*)d_in[k++];
            bb[i][l] = (const float*)d_in[k++];
        }
    float* out = (float*)d_out;

    const size_t NJ1 = (size_t)B_ * M_ * 32;        // 131072
    float* bufA = (float*)d_ws;                     // 96 rows  x 131072
    float* bufB = bufA + 96 * NJ1;                  // 64 rows  x 131072
    float* Ymax = bufB + 64 * NJ1;                  // 128 x 4096
    float* pS   = Ymax + 128 * (B_ * M_);           // 128 x 1024
    float* pS2  = pS + 128 * GXMAX;                 // 128 x 1024
    float* ss   = pS2 + 128 * GXMAX;                // 256
    int* idxbuf = (int*)(ss + 256);                 // B*M*32

    k_gather<<<16, 256, 0, stream>>>(xyz, inds, out);

    // ---------- scale 0: r=0.4, ns=16, layers 67->64->64->128 ----------
    {
        const int NS = 16;
        const int Nj = B_ * M_ * NS;  // 65536
        const int gx = Nj / 128;      // 512
        k_ball<<<1024, 256, 0, stream>>>(xyz, inds, idxbuf, (float)(0.4 * 0.4), NS);
        k_group<<<Nj / 256, 256, 0, stream>>>(xyz, feats, out, idxbuf, bufA, NS, Nj);
        k_gemm<4, false, 0><<<dim3(gx, 1), 256, 0, stream>>>(w[0][0], bufA, ss, bufB, pS, pS2, 67, Nj);
        k_fin<<<64, 256, 0, stream>>>(pS, pS2, gg[0][0], bb[0][0], ss, gx, 1.f / Nj);
        k_gemm<4, true, 0><<<dim3(gx, 1), 256, 0, stream>>>(w[0][1], bufB, ss, bufA, pS, pS2, 64, Nj);
        k_fin<<<64, 256, 0, stream>>>(pS, pS2, gg[0][1], bb[0][1], ss, gx, 1.f / Nj);
        k_gemm<4, true, 16><<<dim3(gx, 2), 256, 0, stream>>>(w[0][2], bufA, ss, Ymax, pS, pS2, 64, Nj);
        k_fin<<<128, 256, 0, stream>>>(pS, pS2, gg[0][2], bb[0][2], ss, gx, 1.f / Nj);
        k_poolfin<<<(B_ * 128 * M_) / 256, 256, 0, stream>>>(Ymax, ss, out, 0);
    }

    // ---------- scale 1: r=0.8, ns=32, layers 67->64->96->128 ----------
    {
        const int NS = 32;
        const int Nj = B_ * M_ * NS;  // 131072
        const int gx = Nj / 128;      // 1024
        k_ball<<<1024, 256, 0, stream>>>(xyz, inds, idxbuf, (float)(0.8 * 0.8), NS);
        k_group<<<Nj / 256, 256, 0, stream>>>(xyz, feats, out, idxbuf, bufA, NS, Nj);
        k_gemm<4, false, 0><<<dim3(gx, 1), 256, 0, stream>>>(w[1][0], bufA, ss, bufB, pS, pS2, 67, Nj);
        k_fin<<<64, 256, 0, stream>>>(pS, pS2, gg[1][0], bb[1][0], ss, gx, 1.f / Nj);
        k_gemm<6, true, 0><<<dim3(gx, 1), 256, 0, stream>>>(w[1][1], bufB, ss, bufA, pS, pS2, 64, Nj);
        k_fin<<<96, 256, 0, stream>>>(pS, pS2, gg[1][1], bb[1][1], ss, gx, 1.f / Nj);
        k_gemm<4, true, 32><<<dim3(gx, 2), 256, 0, stream>>>(w[1][2], bufA, ss, Ymax, pS, pS2, 96, Nj);
        k_fin<<<128, 256, 0, stream>>>(pS, pS2, gg[1][2], bb[1][2], ss, gx, 1.f / Nj);
        k_poolfin<<<(B_ * 128 * M_) / 256, 256, 0, stream>>>(Ymax, ss, out, 128);
    }
}

// Round 3
// 177.955 us; speedup vs baseline: 2.9593x; 1.4272x over previous
//
#include <hip/hip_runtime.h>
#include <math.h>

#define B_ 4
#define N_ 16384
#define M_ 1024
#define C_ 64

// output layout (floats): new_xyz [B*M*3] | feats [B*256*M] | inds [B*M]
#define OUT_XYZ_ELEMS (B_ * M_ * 3)
#define OUT_FEAT_ELEMS (B_ * 256 * M_)
#define PST 2048  // partial-stats stride (max gridx*4)

typedef __attribute__((ext_vector_type(8))) short bf16x8;
typedef __attribute__((ext_vector_type(4))) float f32x4;

__device__ __forceinline__ unsigned short f2bf(float f) {
    unsigned int u = __float_as_uint(f);
    u += 0x7fffu + ((u >> 16) & 1u);
    return (unsigned short)(u >> 16);
}
__device__ __forceinline__ float bf2f(unsigned short h) {
    return __uint_as_float(((unsigned int)h) << 16);
}

// ------------------------------------------------------------------
__global__ void k_gather(const float* __restrict__ xyz, const int* __restrict__ inds,
                         float* __restrict__ out) {
    int t = blockIdx.x * blockDim.x + threadIdx.x;
    if (t >= B_ * M_) return;
    int n = inds[t];
    int b = t / M_;
    const float* p = xyz + ((size_t)b * N_ + n) * 3;
    out[t * 3 + 0] = p[0];
    out[t * 3 + 1] = p[1];
    out[t * 3 + 2] = p[2];
    out[OUT_XYZ_ELEMS + OUT_FEAT_ELEMS + t] = (float)n;
}

// ------------------------------------------------------------------
// ball query: one wave per query, first-NS-in-index-order semantics
__global__ void k_ball(const float* __restrict__ xyz, const int* __restrict__ inds,
                       int* __restrict__ idxbuf, float r2, int NS) {
    int lane = threadIdx.x & 63;
    int t = blockIdx.x * (blockDim.x >> 6) + (threadIdx.x >> 6);
    if (t >= B_ * M_) return;
    int b = t / M_;
    int n0 = inds[t];
    const float* bp = xyz + (size_t)b * N_ * 3;
    float qx = bp[n0 * 3 + 0], qy = bp[n0 * 3 + 1], qz = bp[n0 * 3 + 2];
    int cnt = 0;
    int first = n0;
    for (int base = 0; base < N_ && cnt < NS; base += 64) {
        int n = base + lane;
        float dx = __fsub_rn(qx, bp[n * 3 + 0]);
        float dy = __fsub_rn(qy, bp[n * 3 + 1]);
        float dz = __fsub_rn(qz, bp[n * 3 + 2]);
        float d2 = __fadd_rn(__fadd_rn(__fmul_rn(dx, dx), __fmul_rn(dy, dy)), __fmul_rn(dz, dz));
        unsigned long long mask = __ballot(d2 < r2);
        while (mask && cnt < NS) {
            int bit = (int)__builtin_ctzll(mask);
            int nn = base + bit;
            if (cnt == 0) first = nn;
            if (lane == 0) idxbuf[t * NS + cnt] = nn;
            cnt++;
            mask &= mask - 1;
        }
    }
    for (int k2 = cnt + lane; k2 < NS; k2 += 64) idxbuf[t * NS + k2] = first;
}

// ------------------------------------------------------------------
// grouped input, bf16-packed B-operand layout: Xp[c>>3][j][c&7], 12 chunks (c padded to 96)
__global__ void k_group(const float* __restrict__ xyz, const float* __restrict__ feats,
                        const float* __restrict__ newxyz, const int* __restrict__ idxbuf,
                        unsigned short* __restrict__ Xp, int nslog, int Nj) {
    int j = blockIdx.x * blockDim.x + threadIdx.x;
    if (j >= Nj) return;
    int bm = j >> nslog;
    int b = bm >> 10;
    int nidx = idxbuf[j];
    const float* p = xyz + ((size_t)b * N_ + nidx) * 3;
    float vals[96];
    vals[0] = p[0] - newxyz[bm * 3 + 0];
    vals[1] = p[1] - newxyz[bm * 3 + 1];
    vals[2] = p[2] - newxyz[bm * 3 + 2];
    const float* f = feats + (size_t)b * C_ * N_ + nidx;
    #pragma unroll
    for (int cc = 0; cc < 64; ++cc) vals[3 + cc] = f[(size_t)cc * N_];
    #pragma unroll
    for (int c = 67; c < 96; ++c) vals[c] = 0.f;
    unsigned int u[48];
    #pragma unroll
    for (int k2 = 0; k2 < 48; ++k2)
        u[k2] = (unsigned int)f2bf(vals[2 * k2]) | ((unsigned int)f2bf(vals[2 * k2 + 1]) << 16);
    #pragma unroll
    for (int ch = 0; ch < 12; ++ch)
        *(uint4*)&Xp[((size_t)ch * Nj + j) * 8] = make_uint4(u[ch * 4], u[ch * 4 + 1], u[ch * 4 + 2], u[ch * 4 + 3]);
}

// ------------------------------------------------------------------
// MFMA GEMM: Y[o][j] = sum_c W[o][c]*x[c][j]; x = BN? relu(sc*X+sh) : X.
// A = W tile (16o x 32c), B = X tile (32c x 16j), D = 16x16.
// Per wave: OT o-tiles x 16 j, 4 j-tiles sequentially (TPW=4).
// Epilogue: partial stats always; NSPOOL? fused max-pool to Ymax[bm][coutT] : packed bf16 Yp.
template <int KB, int OT, bool BN, int NSPOOL>
__global__ __launch_bounds__(256) void k_mm(const float* __restrict__ W,
                                            const unsigned short* __restrict__ Xp,
                                            const float* __restrict__ ssin,
                                            unsigned short* __restrict__ Yp,
                                            float* __restrict__ Ymax,
                                            float* __restrict__ pS,
                                            float* __restrict__ pS2,
                                            int cin, int Nj) {
    __shared__ unsigned short Wa[KB * OT * 512];
    const int tid = threadIdx.x;
    const int lane = tid & 63;
    const int wid = tid >> 6;
    const int q = lane >> 4;
    const int jl = lane & 15;
    const int oybase = blockIdx.y * OT * 16;

    // stage A-fragments into LDS (zero-pad c >= cin)
    for (int s = tid; s < KB * OT * 64; s += 256) {
        int kb = s / (OT * 64);
        int r = s - kb * (OT * 64);
        int ot = r >> 6;
        int sl = r & 63;
        int o = oybase + ot * 16 + (sl & 15);
        int cbase = kb * 32 + (sl >> 4) * 8;
        unsigned int pk[4];
        #pragma unroll
        for (int e2 = 0; e2 < 4; ++e2) {
            int c0 = cbase + e2 * 2, c1 = c0 + 1;
            unsigned short lo = (c0 < cin) ? f2bf(W[(size_t)o * cin + c0]) : (unsigned short)0;
            unsigned short hi = (c1 < cin) ? f2bf(W[(size_t)o * cin + c1]) : (unsigned short)0;
            pk[e2] = (unsigned int)lo | ((unsigned int)hi << 16);
        }
        *(uint4*)&Wa[(size_t)s * 8] = make_uint4(pk[0], pk[1], pk[2], pk[3]);
    }
    __syncthreads();

    bf16x8 a[KB][OT];
    #pragma unroll
    for (int kb = 0; kb < KB; ++kb)
        #pragma unroll
        for (int ot = 0; ot < OT; ++ot)
            a[kb][ot] = *(const bf16x8*)&Wa[((kb * OT + ot) * 64 + lane) * 8];

    float sc[KB][8], sh[KB][8];
    if (BN) {
        #pragma unroll
        for (int kb = 0; kb < KB; ++kb)
            #pragma unroll
            for (int e = 0; e < 8; ++e) {
                int c = kb * 32 + q * 8 + e;
                sc[kb][e] = ssin[c * 2 + 0];
                sh[kb][e] = ssin[c * 2 + 1];
            }
    }

    float s1_[OT][4], s2_[OT][4], rmax[OT][4];
    #pragma unroll
    for (int ot = 0; ot < OT; ++ot)
        #pragma unroll
        for (int r = 0; r < 4; ++r) { s1_[ot][r] = 0.f; s2_[ot][r] = 0.f; rmax[ot][r] = 0.f; }

    const int wtile0 = (blockIdx.x * 4 + wid) * 4;
    #pragma unroll
    for (int i = 0; i < 4; ++i) {
        const int t = wtile0 + i;
        const int jj = t * 16 + jl;
        f32x4 acc[OT];
        #pragma unroll
        for (int ot = 0; ot < OT; ++ot) acc[ot] = (f32x4){0.f, 0.f, 0.f, 0.f};

        #pragma unroll
        for (int kb = 0; kb < KB; ++kb) {
            bf16x8 bf = *(const bf16x8*)&Xp[((size_t)(kb * 4 + q) * Nj + jj) * 8];
            if (BN) {
                bf16x8 nb;
                #pragma unroll
                for (int e = 0; e < 8; ++e) {
                    float x = bf2f((unsigned short)bf[e]);
                    float z = fmaxf(fmaf(x, sc[kb][e], sh[kb][e]), 0.f);
                    nb[e] = (short)f2bf(z);
                }
                bf = nb;
            }
            #pragma unroll
            for (int ot = 0; ot < OT; ++ot)
                acc[ot] = __builtin_amdgcn_mfma_f32_16x16x32_bf16(a[kb][ot], bf, acc[ot], 0, 0, 0);
        }

        // running stats (per-lane over its j's)
        #pragma unroll
        for (int ot = 0; ot < OT; ++ot)
            #pragma unroll
            for (int r = 0; r < 4; ++r) {
                float v = acc[ot][r];
                s1_[ot][r] += v;
                s2_[ot][r] = fmaf(v, v, s2_[ot][r]);
            }

        if (NSPOOL == 0) {
            #pragma unroll
            for (int ot = 0; ot < OT; ++ot) {
                int o0 = oybase + ot * 16 + q * 4;
                unsigned int lo = (unsigned int)f2bf(acc[ot][0]) | ((unsigned int)f2bf(acc[ot][1]) << 16);
                unsigned int hi = (unsigned int)f2bf(acc[ot][2]) | ((unsigned int)f2bf(acc[ot][3]) << 16);
                *(uint2*)&Yp[((size_t)(o0 >> 3) * Nj + jj) * 8 + (o0 & 7)] = make_uint2(lo, hi);
            }
        } else if (NSPOOL == 16 || (i & 1) == 1) {
            float mm[OT][4];
            #pragma unroll
            for (int ot = 0; ot < OT; ++ot)
                #pragma unroll
                for (int r = 0; r < 4; ++r)
                    mm[ot][r] = (NSPOOL == 32) ? fmaxf(rmax[ot][r], acc[ot][r]) : acc[ot][r];
            #pragma unroll
            for (int ot = 0; ot < OT; ++ot)
                #pragma unroll
                for (int r = 0; r < 4; ++r) {
                    float v = mm[ot][r];
                    v = fmaxf(v, __shfl_xor(v, 1));
                    v = fmaxf(v, __shfl_xor(v, 2));
                    v = fmaxf(v, __shfl_xor(v, 4));
                    v = fmaxf(v, __shfl_xor(v, 8));
                    mm[ot][r] = v;
                }
            if (jl == 0) {
                int bm = (NSPOOL == 32) ? (t >> 1) : t;
                #pragma unroll
                for (int ot = 0; ot < OT; ++ot)
                    *(float4*)&Ymax[(size_t)bm * 128 + oybase + ot * 16 + q * 4] =
                        make_float4(mm[ot][0], mm[ot][1], mm[ot][2], mm[ot][3]);
            }
        } else {  // NSPOOL==32, even tile: save running max
            #pragma unroll
            for (int ot = 0; ot < OT; ++ot)
                #pragma unroll
                for (int r = 0; r < 4; ++r) rmax[ot][r] = acc[ot][r];
        }
    }

    // reduce stats over the 16 j-lanes, write per-(block,wave) partials
    #pragma unroll
    for (int ot = 0; ot < OT; ++ot)
        #pragma unroll
        for (int r = 0; r < 4; ++r) {
            float v1 = s1_[ot][r], v2 = s2_[ot][r];
            v1 += __shfl_xor(v1, 1); v2 += __shfl_xor(v2, 1);
            v1 += __shfl_xor(v1, 2); v2 += __shfl_xor(v2, 2);
            v1 += __shfl_xor(v1, 4); v2 += __shfl_xor(v2, 4);
            v1 += __shfl_xor(v1, 8); v2 += __shfl_xor(v2, 8);
            s1_[ot][r] = v1; s2_[ot][r] = v2;
        }
    if (jl == 0) {
        int pidx = blockIdx.x * 4 + wid;
        #pragma unroll
        for (int ot = 0; ot < OT; ++ot)
            #pragma unroll
            for (int r = 0; r < 4; ++r) {
                int o = oybase + ot * 16 + q * 4 + r;
                pS[(size_t)o * PST + pidx] = s1_[ot][r];
                pS2[(size_t)o * PST + pidx] = s2_[ot][r];
            }
    }
}

// ------------------------------------------------------------------
__global__ __launch_bounds__(256) void k_fin(const float* __restrict__ pS,
                                             const float* __restrict__ pS2,
                                             const float* __restrict__ gam,
                                             const float* __restrict__ bet,
                                             float* __restrict__ ss, int gx4, float invN) {
    int o = blockIdx.x;
    float s = 0.f, s2 = 0.f;
    for (int i = threadIdx.x; i < gx4; i += 256) {
        s += pS[(size_t)o * PST + i];
        s2 += pS2[(size_t)o * PST + i];
    }
    #pragma unroll
    for (int off = 1; off < 64; off <<= 1) {
        s += __shfl_xor(s, off, 64);
        s2 += __shfl_xor(s2, off, 64);
    }
    __shared__ float ls[4], ls2[4];
    int wid = threadIdx.x >> 6;
    if ((threadIdx.x & 63) == 0) { ls[wid] = s; ls2[wid] = s2; }
    __syncthreads();
    if (threadIdx.x == 0) {
        float S = ls[0] + ls[1] + ls[2] + ls[3];
        float S2 = ls2[0] + ls2[1] + ls2[2] + ls2[3];
        float mean = S * invN;
        float var = S2 * invN - mean * mean;
        float scale = gam[o] / sqrtf(var + 1e-5f);
        float shift = bet[o] - mean * scale;
        ss[o * 2 + 0] = scale;
        ss[o * 2 + 1] = shift;
    }
}

// ------------------------------------------------------------------
// BN+ReLU on pooled raw maxima + transpose [bm][o] -> out[b][o][m]
__global__ __launch_bounds__(256) void k_poolfin(const float* __restrict__ Ymax,
                                                 const float* __restrict__ ss,
                                                 float* __restrict__ out, int o_off) {
    __shared__ float T[128][65];
    int blk = blockIdx.x;  // b*16 + mc
    int b = blk >> 4, mc = blk & 15;
    int bm0 = b * M_ + mc * 64;
    for (int s = threadIdx.x; s < 64 * 32; s += 256) {
        int row = s >> 5;
        int c4 = s & 31;
        float4 v = *(const float4*)&Ymax[(size_t)(bm0 + row) * 128 + c4 * 4];
        T[c4 * 4 + 0][row] = v.x;
        T[c4 * 4 + 1][row] = v.y;
        T[c4 * 4 + 2][row] = v.z;
        T[c4 * 4 + 3][row] = v.w;
    }
    __syncthreads();
    for (int s = threadIdx.x; s < 128 * 16; s += 256) {
        int o = s >> 4, m4 = s & 15;
        float scv = ss[o * 2 + 0], shv = ss[o * 2 + 1];
        float4 v = make_float4(T[o][m4 * 4], T[o][m4 * 4 + 1], T[o][m4 * 4 + 2], T[o][m4 * 4 + 3]);
        v.x = fmaxf(fmaf(v.x, scv, shv), 0.f);
        v.y = fmaxf(fmaf(v.y, scv, shv), 0.f);
        v.z = fmaxf(fmaf(v.z, scv, shv), 0.f);
        v.w = fmaxf(fmaf(v.w, scv, shv), 0.f);
        *(float4*)&out[OUT_XYZ_ELEMS + ((size_t)(b * 256 + o_off + o)) * M_ + mc * 64 + m4 * 4] = v;
    }
}

// ------------------------------------------------------------------
extern "C" void kernel_launch(void* const* d_in, const int* in_sizes, int n_in,
                              void* d_out, int out_size, void* d_ws, size_t ws_size,
                              hipStream_t stream) {
    const float* xyz = (const float*)d_in[0];
    const float* feats = (const float*)d_in[1];
    const int* inds = (const int*)d_in[2];
    const float* w[2][3];
    const float* gg[2][3];
    const float* bb[2][3];
    int k = 3;
    for (int i = 0; i < 2; ++i)
        for (int l = 0; l < 3; ++l) {
            w[i][l] = (const float*)d_in[k++];
            gg[i][l] = (const float*)d_in[k++];
            bb[i][l] = (const float*)d_in[k++];
        }
    float* out = (float*)d_out;

    const size_t NJ1 = (size_t)B_ * M_ * 32;            // 131072
    unsigned short* bufA = (unsigned short*)d_ws;       // 12 chunks x NJ1 x 8 bf16
    unsigned short* bufB = bufA + (size_t)12 * NJ1 * 8;
    float* Ymax = (float*)(bufB + (size_t)12 * NJ1 * 8);  // [4096][128]
    float* pS = Ymax + (size_t)B_ * M_ * 128;
    float* pS2 = pS + (size_t)128 * PST;
    float* ss = pS2 + (size_t)128 * PST;
    int* idxbuf = (int*)(ss + 256);

    k_gather<<<16, 256, 0, stream>>>(xyz, inds, out);

    // ---------- scale 0: r=0.4, ns=16, 67->64->64->128 ----------
    {
        const int Nj = B_ * M_ * 16;  // 65536
        const int gx = Nj / 256;      // 256 blocks (4 waves x 4 tiles x 16 j)
        k_ball<<<1024, 256, 0, stream>>>(xyz, inds, idxbuf, (float)(0.4 * 0.4), 16);
        k_group<<<Nj / 256, 256, 0, stream>>>(xyz, feats, out, idxbuf, bufA, 4, Nj);
        k_mm<3, 4, false, 0><<<dim3(gx, 1), 256, 0, stream>>>(w[0][0], bufA, ss, bufB, nullptr, pS, pS2, 67, Nj);
        k_fin<<<64, 256, 0, stream>>>(pS, pS2, gg[0][0], bb[0][0], ss, gx * 4, 1.f / Nj);
        k_mm<2, 4, true, 0><<<dim3(gx, 1), 256, 0, stream>>>(w[0][1], bufB, ss, bufA, nullptr, pS, pS2, 64, Nj);
        k_fin<<<64, 256, 0, stream>>>(pS, pS2, gg[0][1], bb[0][1], ss, gx * 4, 1.f / Nj);
        k_mm<2, 4, true, 16><<<dim3(gx, 2), 256, 0, stream>>>(w[0][2], bufA, ss, nullptr, Ymax, pS, pS2, 64, Nj);
        k_fin<<<128, 256, 0, stream>>>(pS, pS2, gg[0][2], bb[0][2], ss, gx * 4, 1.f / Nj);
        k_poolfin<<<64, 256, 0, stream>>>(Ymax, ss, out, 0);
    }

    // ---------- scale 1: r=0.8, ns=32, 67->64->96->128 ----------
    {
        const int Nj = B_ * M_ * 32;  // 131072
        const int gx = Nj / 256;      // 512 blocks
        k_ball<<<1024, 256, 0, stream>>>(xyz, inds, idxbuf, (float)(0.8 * 0.8), 32);
        k_group<<<Nj / 256, 256, 0, stream>>>(xyz, feats, out, idxbuf, bufA, 5, Nj);
        k_mm<3, 4, false, 0><<<dim3(gx, 1), 256, 0, stream>>>(w[1][0], bufA, ss, bufB, nullptr, pS, pS2, 67, Nj);
        k_fin<<<64, 256, 0, stream>>>(pS, pS2, gg[1][0], bb[1][0], ss, gx * 4, 1.f / Nj);
        k_mm<2, 6, true, 0><<<dim3(gx, 1), 256, 0, stream>>>(w[1][1], bufB, ss, bufA, nullptr, pS, pS2, 64, Nj);
        k_fin<<<96, 256, 0, stream>>>(pS, pS2, gg[1][1], bb[1][1], ss, gx * 4, 1.f / Nj);
        k_mm<3, 4, true, 32><<<dim3(gx, 2), 256, 0, stream>>>(w[1][2], bufA, ss, nullptr, Ymax, pS, pS2, 96, Nj);
        k_fin<<<128, 256, 0, stream>>>(pS, pS2, gg[1][2], bb[1][2], ss, gx * 4, 1.f / Nj);
        k_poolfin<<<64, 256, 0, stream>>>(Ymax, ss, out, 128);
    }
}

// Round 4
// 161.651 us; speedup vs baseline: 3.2578x; 1.1009x over previous
//
#include <hip/hip_runtime.h>
#include <math.h>

#define B_ 4
#define N_ 16384
#define M_ 1024
#define C_ 64

// output layout (floats): new_xyz [B*M*3] | feats [B*256*M] | inds [B*M]
#define OUT_XYZ_ELEMS (B_ * M_ * 3)
#define OUT_FEAT_ELEMS (B_ * 256 * M_)
#define PST 512  // partial-stats stride (max gridDim.x)

typedef __attribute__((ext_vector_type(8))) short bf16x8;
typedef __attribute__((ext_vector_type(4))) float f32x4;

__device__ __forceinline__ unsigned short f2bf(float f) {
    unsigned int u = __float_as_uint(f);
    u += 0x7fffu + ((u >> 16) & 1u);
    return (unsigned short)(u >> 16);
}
__device__ __forceinline__ float bf2f(unsigned short h) {
    return __uint_as_float(((unsigned int)h) << 16);
}

// ------------------------------------------------------------------
__global__ void k_gather(const float* __restrict__ xyz, const int* __restrict__ inds,
                         float* __restrict__ out) {
    int t = blockIdx.x * blockDim.x + threadIdx.x;
    if (t >= B_ * M_) return;
    int n = inds[t];
    int b = t / M_;
    const float* p = xyz + ((size_t)b * N_ + n) * 3;
    out[t * 3 + 0] = p[0];
    out[t * 3 + 1] = p[1];
    out[t * 3 + 2] = p[2];
    out[OUT_XYZ_ELEMS + OUT_FEAT_ELEMS + t] = (float)n;
}

// ------------------------------------------------------------------
// transpose feats (B,C,N) f32 -> featsT (B,N,64) bf16
__global__ __launch_bounds__(256) void k_trans(const float* __restrict__ feats,
                                               unsigned short* __restrict__ featsT) {
    __shared__ unsigned short T[64][72];
    int blk = blockIdx.x;        // b*256 + nblk
    int b = blk >> 8;
    int n0 = (blk & 255) << 6;
    int tn = threadIdx.x & 63;
    int c0 = threadIdx.x >> 6;   // 0..3
    const float* fp = feats + (size_t)b * C_ * N_ + n0 + tn;
    #pragma unroll
    for (int it = 0; it < 16; ++it) {
        int c = it * 4 + c0;
        T[c][tn] = f2bf(fp[(size_t)c * N_]);
    }
    __syncthreads();
    for (int s = threadIdx.x; s < 64 * 8; s += 256) {
        int n = s >> 3, ch = s & 7;
        unsigned int pk[4];
        #pragma unroll
        for (int e = 0; e < 4; ++e)
            pk[e] = (unsigned int)T[ch * 8 + e * 2][n] | ((unsigned int)T[ch * 8 + e * 2 + 1][n] << 16);
        *(uint4*)&featsT[(((size_t)b * N_ + n0 + n) << 6) + ch * 8] =
            make_uint4(pk[0], pk[1], pk[2], pk[3]);
    }
}

// ------------------------------------------------------------------
// ball query: one wave per query, first-NS-in-index-order semantics
__global__ void k_ball(const float* __restrict__ xyz, const int* __restrict__ inds,
                       int* __restrict__ idxbuf, float r2, int NS) {
    int lane = threadIdx.x & 63;
    int t = blockIdx.x * (blockDim.x >> 6) + (threadIdx.x >> 6);
    if (t >= B_ * M_) return;
    int b = t / M_;
    int n0 = inds[t];
    const float* bp = xyz + (size_t)b * N_ * 3;
    float qx = bp[n0 * 3 + 0], qy = bp[n0 * 3 + 1], qz = bp[n0 * 3 + 2];
    int cnt = 0;
    int first = n0;
    for (int base = 0; base < N_ && cnt < NS; base += 64) {
        int n = base + lane;
        float dx = __fsub_rn(qx, bp[n * 3 + 0]);
        float dy = __fsub_rn(qy, bp[n * 3 + 1]);
        float dz = __fsub_rn(qz, bp[n * 3 + 2]);
        float d2 = __fadd_rn(__fadd_rn(__fmul_rn(dx, dx), __fmul_rn(dy, dy)), __fmul_rn(dz, dz));
        unsigned long long mask = __ballot(d2 < r2);
        while (mask && cnt < NS) {
            int bit = (int)__builtin_ctzll(mask);
            int nn = base + bit;
            if (cnt == 0) first = nn;
            if (lane == 0) idxbuf[t * NS + cnt] = nn;
            cnt++;
            mask &= mask - 1;
        }
    }
    for (int k2 = cnt + lane; k2 < NS; k2 += 64) idxbuf[t * NS + k2] = first;
}

// ------------------------------------------------------------------
// MFMA GEMM: Y[o][j] = sum_c W[o][c]*x[c][j].
// GATHER: layer0 — B-fragments gathered directly from featsT (channels
//   permuted: c'=0..63 feats, c'=64..66 rel-xyz, pad to 96; W rows permuted
//   to match). No Xp input.
// else: x read from packed Xp[c>>3][j][c&7]; BN? x=relu(sc*X+sh).
// Epilogue: per-block channel partial stats; NSPOOL? fused max-pool : bf16 Yp.
template <int KB, int OT, bool BN, int NSPOOL, bool GATHER>
__global__ __launch_bounds__(256) void k_mm(const float* __restrict__ W,
                                            const unsigned short* __restrict__ Xp,
                                            const float* __restrict__ ssin,
                                            unsigned short* __restrict__ Yp,
                                            float* __restrict__ Ymax,
                                            float* __restrict__ pS,
                                            float* __restrict__ pS2,
                                            int cin, int Nj,
                                            const unsigned short* __restrict__ featsT,
                                            const float* __restrict__ xyz,
                                            const float* __restrict__ newxyz,
                                            const int* __restrict__ idxbuf,
                                            int nslog) {
    __shared__ unsigned short Wa[KB * OT * 512];
    __shared__ float sm1[4][OT * 16];
    __shared__ float sm2[4][OT * 16];
    const int tid = threadIdx.x;
    const int lane = tid & 63;
    const int wid = tid >> 6;
    const int q = lane >> 4;
    const int jl = lane & 15;
    const int oybase = blockIdx.y * OT * 16;

    // stage A-fragments into LDS
    for (int s = tid; s < KB * OT * 64; s += 256) {
        int kb = s / (OT * 64);
        int r = s - kb * (OT * 64);
        int ot = r >> 6;
        int sl = r & 63;
        int o = oybase + ot * 16 + (sl & 15);
        int cbase = kb * 32 + (sl >> 4) * 8;
        unsigned int pk[4];
        #pragma unroll
        for (int e2 = 0; e2 < 4; ++e2) {
            int c0 = cbase + e2 * 2, c1 = c0 + 1;
            unsigned short lo, hi;
            if (GATHER) {
                lo = (c0 < 64) ? f2bf(W[(size_t)o * 67 + 3 + c0])
                               : (c0 < 67 ? f2bf(W[(size_t)o * 67 + c0 - 64]) : (unsigned short)0);
                hi = (c1 < 64) ? f2bf(W[(size_t)o * 67 + 3 + c1])
                               : (c1 < 67 ? f2bf(W[(size_t)o * 67 + c1 - 64]) : (unsigned short)0);
            } else {
                lo = (c0 < cin) ? f2bf(W[(size_t)o * cin + c0]) : (unsigned short)0;
                hi = (c1 < cin) ? f2bf(W[(size_t)o * cin + c1]) : (unsigned short)0;
            }
            pk[e2] = (unsigned int)lo | ((unsigned int)hi << 16);
        }
        *(uint4*)&Wa[(size_t)s * 8] = make_uint4(pk[0], pk[1], pk[2], pk[3]);
    }
    __syncthreads();

    bf16x8 a[KB][OT];
    #pragma unroll
    for (int kb = 0; kb < KB; ++kb)
        #pragma unroll
        for (int ot = 0; ot < OT; ++ot)
            a[kb][ot] = *(const bf16x8*)&Wa[((kb * OT + ot) * 64 + lane) * 8];

    float sc[KB][8], sh[KB][8];
    if (BN) {
        #pragma unroll
        for (int kb = 0; kb < KB; ++kb)
            #pragma unroll
            for (int e = 0; e < 8; ++e) {
                int c = kb * 32 + q * 8 + e;
                sc[kb][e] = ssin[c * 2 + 0];
                sh[kb][e] = ssin[c * 2 + 1];
            }
    }

    float s1_[OT][4], s2_[OT][4], rmax[OT][4];
    #pragma unroll
    for (int ot = 0; ot < OT; ++ot)
        #pragma unroll
        for (int r = 0; r < 4; ++r) { s1_[ot][r] = 0.f; s2_[ot][r] = 0.f; rmax[ot][r] = 0.f; }

    const int wtile0 = (blockIdx.x * 4 + wid) * 4;
    #pragma unroll
    for (int i = 0; i < 4; ++i) {
        const int t = wtile0 + i;
        const int jj = t * 16 + jl;
        f32x4 acc[OT];
        #pragma unroll
        for (int ot = 0; ot < OT; ++ot) acc[ot] = (f32x4){0.f, 0.f, 0.f, 0.f};

        const unsigned short* fr_row = nullptr;
        float rx = 0.f, ry = 0.f, rz = 0.f;
        if (GATHER) {
            int bm = jj >> nslog;
            int b = bm >> 10;
            int nidx = idxbuf[jj];
            fr_row = featsT + (((size_t)b * N_ + nidx) << 6);
            const float* pp = xyz + ((size_t)b * N_ + nidx) * 3;
            rx = __fsub_rn(pp[0], newxyz[bm * 3 + 0]);
            ry = __fsub_rn(pp[1], newxyz[bm * 3 + 1]);
            rz = __fsub_rn(pp[2], newxyz[bm * 3 + 2]);
        }

        #pragma unroll
        for (int kb = 0; kb < KB; ++kb) {
            bf16x8 bf;
            if (GATHER) {
                if (kb < 2) {
                    bf = *(const bf16x8*)&fr_row[kb * 32 + q * 8];
                } else {
                    bf = (bf16x8){0, 0, 0, 0, 0, 0, 0, 0};
                    if (q == 0) {
                        bf[0] = (short)f2bf(rx);
                        bf[1] = (short)f2bf(ry);
                        bf[2] = (short)f2bf(rz);
                    }
                }
            } else {
                bf = *(const bf16x8*)&Xp[((size_t)(kb * 4 + q) * Nj + jj) * 8];
                if (BN) {
                    bf16x8 nb;
                    #pragma unroll
                    for (int e = 0; e < 8; ++e) {
                        float x = bf2f((unsigned short)bf[e]);
                        float z = fmaxf(fmaf(x, sc[kb][e], sh[kb][e]), 0.f);
                        nb[e] = (short)f2bf(z);
                    }
                    bf = nb;
                }
            }
            #pragma unroll
            for (int ot = 0; ot < OT; ++ot)
                acc[ot] = __builtin_amdgcn_mfma_f32_16x16x32_bf16(a[kb][ot], bf, acc[ot], 0, 0, 0);
        }

        #pragma unroll
        for (int ot = 0; ot < OT; ++ot)
            #pragma unroll
            for (int r = 0; r < 4; ++r) {
                float v = acc[ot][r];
                s1_[ot][r] += v;
                s2_[ot][r] = fmaf(v, v, s2_[ot][r]);
            }

        if (NSPOOL == 0) {
            #pragma unroll
            for (int ot = 0; ot < OT; ++ot) {
                int o0 = oybase + ot * 16 + q * 4;
                unsigned int lo = (unsigned int)f2bf(acc[ot][0]) | ((unsigned int)f2bf(acc[ot][1]) << 16);
                unsigned int hi = (unsigned int)f2bf(acc[ot][2]) | ((unsigned int)f2bf(acc[ot][3]) << 16);
                *(uint2*)&Yp[((size_t)(o0 >> 3) * Nj + jj) * 8 + (o0 & 7)] = make_uint2(lo, hi);
            }
        } else if (NSPOOL == 16 || (i & 1) == 1) {
            float mm[OT][4];
            #pragma unroll
            for (int ot = 0; ot < OT; ++ot)
                #pragma unroll
                for (int r = 0; r < 4; ++r)
                    mm[ot][r] = (NSPOOL == 32) ? fmaxf(rmax[ot][r], acc[ot][r]) : acc[ot][r];
            #pragma unroll
            for (int ot = 0; ot < OT; ++ot)
                #pragma unroll
                for (int r = 0; r < 4; ++r) {
                    float v = mm[ot][r];
                    v = fmaxf(v, __shfl_xor(v, 1));
                    v = fmaxf(v, __shfl_xor(v, 2));
                    v = fmaxf(v, __shfl_xor(v, 4));
                    v = fmaxf(v, __shfl_xor(v, 8));
                    mm[ot][r] = v;
                }
            if (jl == 0) {
                int bm = (NSPOOL == 32) ? (t >> 1) : t;
                #pragma unroll
                for (int ot = 0; ot < OT; ++ot)
                    *(float4*)&Ymax[(size_t)bm * 128 + oybase + ot * 16 + q * 4] =
                        make_float4(mm[ot][0], mm[ot][1], mm[ot][2], mm[ot][3]);
            }
        } else {
            #pragma unroll
            for (int ot = 0; ot < OT; ++ot)
                #pragma unroll
                for (int r = 0; r < 4; ++r) rmax[ot][r] = acc[ot][r];
        }
    }

    // reduce stats over 16 j-lanes, stash per-wave rows in LDS
    #pragma unroll
    for (int ot = 0; ot < OT; ++ot)
        #pragma unroll
        for (int r = 0; r < 4; ++r) {
            float v1 = s1_[ot][r], v2 = s2_[ot][r];
            v1 += __shfl_xor(v1, 1); v2 += __shfl_xor(v2, 1);
            v1 += __shfl_xor(v1, 2); v2 += __shfl_xor(v2, 2);
            v1 += __shfl_xor(v1, 4); v2 += __shfl_xor(v2, 4);
            v1 += __shfl_xor(v1, 8); v2 += __shfl_xor(v2, 8);
            s1_[ot][r] = v1; s2_[ot][r] = v2;
        }
    if (jl == 0) {
        #pragma unroll
        for (int ot = 0; ot < OT; ++ot)
            #pragma unroll
            for (int r = 0; r < 4; ++r) {
                sm1[wid][ot * 16 + q * 4 + r] = s1_[ot][r];
                sm2[wid][ot * 16 + q * 4 + r] = s2_[ot][r];
            }
    }
    __syncthreads();
    for (int o = tid; o < OT * 16; o += 256) {
        float a1 = sm1[0][o] + sm1[1][o] + sm1[2][o] + sm1[3][o];
        float a2 = sm2[0][o] + sm2[1][o] + sm2[2][o] + sm2[3][o];
        pS[(size_t)(oybase + o) * PST + blockIdx.x] = a1;
        pS2[(size_t)(oybase + o) * PST + blockIdx.x] = a2;
    }
}

// ------------------------------------------------------------------
// one wave per channel: reduce per-block partials -> scale/shift
__global__ __launch_bounds__(64) void k_fin(const float* __restrict__ pS,
                                            const float* __restrict__ pS2,
                                            const float* __restrict__ gam,
                                            const float* __restrict__ bet,
                                            float* __restrict__ ss, int gx, float invN) {
    int o = blockIdx.x;
    int l = threadIdx.x;
    float s = 0.f, s2 = 0.f;
    for (int i = l; i < gx; i += 64) {
        s += pS[(size_t)o * PST + i];
        s2 += pS2[(size_t)o * PST + i];
    }
    #pragma unroll
    for (int off = 1; off < 64; off <<= 1) {
        s += __shfl_xor(s, off, 64);
        s2 += __shfl_xor(s2, off, 64);
    }
    if (l == 0) {
        float mean = s * invN;
        float var = s2 * invN - mean * mean;
        float scale = gam[o] / sqrtf(var + 1e-5f);
        float shift = bet[o] - mean * scale;
        ss[o * 2 + 0] = scale;
        ss[o * 2 + 1] = shift;
    }
}

// ------------------------------------------------------------------
// BN+ReLU on pooled raw maxima + transpose [bm][o] -> out[b][o][m]
__global__ __launch_bounds__(256) void k_poolfin(const float* __restrict__ Ymax,
                                                 const float* __restrict__ ss,
                                                 float* __restrict__ out, int o_off) {
    __shared__ float T[128][65];
    int blk = blockIdx.x;  // b*16 + mc
    int b = blk >> 4, mc = blk & 15;
    int bm0 = b * M_ + mc * 64;
    for (int s = threadIdx.x; s < 64 * 32; s += 256) {
        int row = s >> 5;
        int c4 = s & 31;
        float4 v = *(const float4*)&Ymax[(size_t)(bm0 + row) * 128 + c4 * 4];
        T[c4 * 4 + 0][row] = v.x;
        T[c4 * 4 + 1][row] = v.y;
        T[c4 * 4 + 2][row] = v.z;
        T[c4 * 4 + 3][row] = v.w;
    }
    __syncthreads();
    for (int s = threadIdx.x; s < 128 * 16; s += 256) {
        int o = s >> 4, m4 = s & 15;
        float scv = ss[o * 2 + 0], shv = ss[o * 2 + 1];
        float4 v = make_float4(T[o][m4 * 4], T[o][m4 * 4 + 1], T[o][m4 * 4 + 2], T[o][m4 * 4 + 3]);
        v.x = fmaxf(fmaf(v.x, scv, shv), 0.f);
        v.y = fmaxf(fmaf(v.y, scv, shv), 0.f);
        v.z = fmaxf(fmaf(v.z, scv, shv), 0.f);
        v.w = fmaxf(fmaf(v.w, scv, shv), 0.f);
        *(float4*)&out[OUT_XYZ_ELEMS + ((size_t)(b * 256 + o_off + o)) * M_ + mc * 64 + m4 * 4] = v;
    }
}

// ------------------------------------------------------------------
extern "C" void kernel_launch(void* const* d_in, const int* in_sizes, int n_in,
                              void* d_out, int out_size, void* d_ws, size_t ws_size,
                              hipStream_t stream) {
    const float* xyz = (const float*)d_in[0];
    const float* feats = (const float*)d_in[1];
    const int* inds = (const int*)d_in[2];
    const float* w[2][3];
    const float* gg[2][3];
    const float* bb[2][3];
    int k = 3;
    for (int i = 0; i < 2; ++i)
        for (int l = 0; l < 3; ++l) {
            w[i][l] = (const float*)d_in[k++];
            gg[i][l] = (const float*)d_in[k++];
            bb[i][l] = (const float*)d_in[k++];
        }
    float* out = (float*)d_out;

    const size_t NJ1 = (size_t)B_ * M_ * 32;              // 131072
    unsigned short* featsT = (unsigned short*)d_ws;       // B*N*64 bf16
    unsigned short* bufA = featsT + (size_t)B_ * N_ * 64;
    unsigned short* bufB = bufA + (size_t)12 * NJ1 * 8;
    float* Ymax = (float*)(bufB + (size_t)12 * NJ1 * 8);  // [4096][128]
    float* pS = Ymax + (size_t)B_ * M_ * 128;
    float* pS2 = pS + (size_t)128 * PST;
    float* ss = pS2 + (size_t)128 * PST;
    int* idxbuf = (int*)(ss + 256);

    k_gather<<<16, 256, 0, stream>>>(xyz, inds, out);
    k_trans<<<B_ * 256, 256, 0, stream>>>(feats, featsT);

    // ---------- scale 0: r=0.4, ns=16, 67->64->64->128 ----------
    {
        const int Nj = B_ * M_ * 16;  // 65536
        const int gx = Nj / 256;      // 256
        k_ball<<<1024, 256, 0, stream>>>(xyz, inds, idxbuf, (float)(0.4 * 0.4), 16);
        k_mm<3, 4, false, 0, true><<<dim3(gx, 1), 256, 0, stream>>>(
            w[0][0], nullptr, ss, bufB, nullptr, pS, pS2, 67, Nj, featsT, xyz, out, idxbuf, 4);
        k_fin<<<64, 64, 0, stream>>>(pS, pS2, gg[0][0], bb[0][0], ss, gx, 1.f / Nj);
        k_mm<2, 4, true, 0, false><<<dim3(gx, 1), 256, 0, stream>>>(
            w[0][1], bufB, ss, bufA, nullptr, pS, pS2, 64, Nj, nullptr, nullptr, nullptr, nullptr, 0);
        k_fin<<<64, 64, 0, stream>>>(pS, pS2, gg[0][1], bb[0][1], ss, gx, 1.f / Nj);
        k_mm<2, 4, true, 16, false><<<dim3(gx, 2), 256, 0, stream>>>(
            w[0][2], bufA, ss, nullptr, Ymax, pS, pS2, 64, Nj, nullptr, nullptr, nullptr, nullptr, 0);
        k_fin<<<128, 64, 0, stream>>>(pS, pS2, gg[0][2], bb[0][2], ss, gx, 1.f / Nj);
        k_poolfin<<<64, 256, 0, stream>>>(Ymax, ss, out, 0);
    }

    // ---------- scale 1: r=0.8, ns=32, 67->64->96->128 ----------
    {
        const int Nj = B_ * M_ * 32;  // 131072
        const int gx = Nj / 256;      // 512
        k_ball<<<1024, 256, 0, stream>>>(xyz, inds, idxbuf, (float)(0.8 * 0.8), 32);
        k_mm<3, 4, false, 0, true><<<dim3(gx, 1), 256, 0, stream>>>(
            w[1][0], nullptr, ss, bufB, nullptr, pS, pS2, 67, Nj, featsT, xyz, out, idxbuf, 5);
        k_fin<<<64, 64, 0, stream>>>(pS, pS2, gg[1][0], bb[1][0], ss, gx, 1.f / Nj);
        k_mm<2, 6, true, 0, false><<<dim3(gx, 1), 256, 0, stream>>>(
            w[1][1], bufB, ss, bufA, nullptr, pS, pS2, 64, Nj, nullptr, nullptr, nullptr, nullptr, 0);
        k_fin<<<96, 64, 0, stream>>>(pS, pS2, gg[1][1], bb[1][1], ss, gx, 1.f / Nj);
        k_mm<3, 4, true, 32, false><<<dim3(gx, 2), 256, 0, stream>>>(
            w[1][2], bufA, ss, nullptr, Ymax, pS, pS2, 96, Nj, nullptr, nullptr, nullptr, nullptr, 0);
        k_fin<<<128, 64, 0, stream>>>(pS, pS2, gg[1][2], bb[1][2], ss, gx, 1.f / Nj);
        k_poolfin<<<64, 256, 0, stream>>>(Ymax, ss, out, 128);
    }
}